// Round 3
// baseline (256.451 us; speedup 1.0000x reference)
//
#include <hip/hip_runtime.h>
#include <math.h>

#define NP 10          // num prototypes
#define NQ 10          // queue length
#define NB 8           // batch
#define TEMP_INV (1.0f/0.07f)
#define DHW (64*128*128)       // 1,048,576 voxels per sample
#define BLOCKS_X 256           // blocks per sample -> 2048 blocks total (8/CU)
#define THREADS 256
#define K_ITERS 4              // float4-pairs per thread: 256*256*4*4 == DHW
#define STRIDE4 (BLOCKS_X*THREADS)   // 65536 float4s

// ---------------------------------------------------------------------------
// Kernel 1: per-voxel argmax over 10 prototypes -> per-block partial histogram.
// Occupancy-tuned: K=4 keeps only 8 float4 loads in flight (~60 VGPR), 2048
// blocks give 8 blocks/CU so latency is hidden by TLP. No atomics: u64 packed
// per-thread histogram (6-bit fields, max 16/field), wave shuffle-reduce,
// per-wave LDS slots, per-block plain global store.
// ---------------------------------------------------------------------------
__global__ __launch_bounds__(THREADS, 6) void hist_kernel(const float* __restrict__ x,
                                                          const float* __restrict__ protos,
                                                          unsigned int* __restrict__ partial) {
    const int b    = blockIdx.y;
    const int tid  = threadIdx.x;
    const int lane = tid & 63;
    const int wave = tid >> 6;

    float p0[NP], p1[NP];
#pragma unroll
    for (int p = 0; p < NP; ++p) {
        p0[p] = protos[p * 2 + 0];
        p1[p] = protos[p * 2 + 1];
    }

    const float4* x0 = (const float4*)(x + (size_t)b * 2 * DHW);
    const float4* x1 = (const float4*)(x + (size_t)b * 2 * DHW + DHW);
    const int i0 = blockIdx.x * THREADS + tid;

    // issue all loads first -> max memory-level parallelism
    float4 a[K_ITERS], c[K_ITERS];
#pragma unroll
    for (int k = 0; k < K_ITERS; ++k) {
        a[k] = x0[i0 + k * STRIDE4];
        c[k] = x1[i0 + k * STRIDE4];
    }

    unsigned long long packed = 0ull;   // 10 x 6-bit counters
#pragma unroll
    for (int k = 0; k < K_ITERS; ++k) {
        float xa[4] = {a[k].x, a[k].y, a[k].z, a[k].w};
        float xc[4] = {c[k].x, c[k].y, c[k].z, c[k].w};
#pragma unroll
        for (int j = 0; j < 4; ++j) {
            float best = xa[j] * p0[0] + xc[j] * p1[0];
            int   bi   = 0;
#pragma unroll
            for (int p = 1; p < NP; ++p) {
                float sim = xa[j] * p0[p] + xc[j] * p1[p];
                if (sim > best) { best = sim; bi = p; }   // strict > == np.argmax first-max
            }
            packed += 1ull << (6 * bi);
        }
    }

    // wave-level reduction of each 6-bit field, then per-wave LDS slot
    __shared__ unsigned int smem[THREADS / 64][NP];
#pragma unroll
    for (int p = 0; p < NP; ++p) {
        unsigned int cc = (unsigned int)((packed >> (6 * p)) & 63ull);
#pragma unroll
        for (int off = 32; off > 0; off >>= 1)
            cc += __shfl_xor(cc, off, 64);
        if (lane == 0) smem[wave][p] = cc;
    }
    __syncthreads();

    if (tid < NP) {
        unsigned int t = smem[0][tid] + smem[1][tid] + smem[2][tid] + smem[3][tid];
        partial[((size_t)b * BLOCKS_X + blockIdx.x) * NP + tid] = t;   // plain store
    }
}

// ---------------------------------------------------------------------------
// Kernel 2: sum partials -> counts; pool = counts @ protos; contrastive loss.
// ---------------------------------------------------------------------------
__global__ void finalize_kernel(const unsigned int* __restrict__ partial,
                                const float* __restrict__ protos,
                                const float* __restrict__ queue0,
                                const float* __restrict__ queue1,
                                float* __restrict__ out) {
    __shared__ float scount[NB][NP];
    __shared__ float ploss[NB];
    const int t = threadIdx.x;

    if (t < NB * NP) {
        const int b = t / NP, p = t % NP;
        unsigned int s = 0;
#pragma unroll 8
        for (int j = 0; j < BLOCKS_X; ++j)
            s += partial[((size_t)b * BLOCKS_X + j) * NP + p];
        scount[b][p] = (float)s;
    }
    __syncthreads();

    if (t < NB) {
        float pool0 = 0.f, pool1 = 0.f;
#pragma unroll
        for (int p = 0; p < NP; ++p) {
            pool0 += scount[t][p] * protos[p * 2 + 0];
            pool1 += scount[t][p] * protos[p * 2 + 1];
        }
        float n = fmaxf(sqrtf(pool0 * pool0 + pool1 * pool1), 1e-12f);
        float pn0 = pool0 / n, pn1 = pool1 / n;

        float ln[NQ];
        float maxlog = -INFINITY;
#pragma unroll
        for (int q = 0; q < NQ; ++q) {
            float f0 = queue0[q * 2], f1 = queue0[q * 2 + 1];
            float nn = fmaxf(sqrtf(f0 * f0 + f1 * f1), 1e-12f);
            float l  = (pn0 * f0 + pn1 * f1) / nn * TEMP_INV;
            ln[q] = l;
            maxlog = fmaxf(maxlog, l);
        }
        float lneg = 0.f;
#pragma unroll
        for (int q = 0; q < NQ; ++q) lneg += expf(ln[q] - maxlog);

        float lsum = 0.f;
#pragma unroll
        for (int q = 0; q < NQ; ++q) {
            float f0 = queue1[q * 2], f1 = queue1[q * 2 + 1];
            float nn = fmaxf(sqrtf(f0 * f0 + f1 * f1), 1e-12f);
            float lp = (pn0 * f0 + pn1 * f1) / nn * TEMP_INV - maxlog;
            float v  = fmaxf(lneg + expf(lp), 1e-4f);
            lsum += -(lp - logf(v));
        }
        ploss[t] = lsum / (float)NQ;
    }
    __syncthreads();
    if (t == 0) {
        float s = 0.f;
#pragma unroll
        for (int i = 0; i < NB; ++i) s += ploss[i];
        out[0] = s / (float)NB;
    }
}

extern "C" void kernel_launch(void* const* d_in, const int* in_sizes, int n_in,
                              void* d_out, int out_size, void* d_ws, size_t ws_size,
                              hipStream_t stream) {
    const float* x      = (const float*)d_in[0];
    // d_in[1] = label — cancels out of the loss exactly; never read.
    const float* protos = (const float*)d_in[2];
    const float* q0     = (const float*)d_in[3];
    const float* q1     = (const float*)d_in[4];
    float* out          = (float*)d_out;

    unsigned int* partial = (unsigned int*)d_ws;   // [8*256][10] u32 = 80 KB
    // No memset needed: every block unconditionally writes its partial row.

    dim3 grid(BLOCKS_X, NB);
    hist_kernel<<<grid, THREADS, 0, stream>>>(x, protos, partial);
    finalize_kernel<<<1, 128, 0, stream>>>(partial, protos, q0, q1, out);
}

// Round 4
// 180.053 us; speedup vs baseline: 1.4243x; 1.4243x over previous
//
#include <hip/hip_runtime.h>
#include <math.h>

#define NP 10          // num prototypes
#define NQ 10          // queue length
#define NB 8           // batch
#define TEMP_INV (1.0f/0.07f)
#define DHW (64*128*128)       // 1,048,576 voxels per sample
#define BLOCKS_X 256           // blocks per sample -> 2048 blocks total (8/CU)
#define THREADS 256
#define K_ITERS 4              // float4-pairs per thread: 256*256*4*4 == DHW
#define STRIDE4 (BLOCKS_X*THREADS)   // 65536 float4s

// ---------------------------------------------------------------------------
// Kernel 1: per-voxel argmax over 10 prototypes -> per-block partial histogram.
// __launch_bounds__(256,4): VGPR cap 128 — above the ~80 natural demand so
// NO scratch spill (R3's (256,6) cap forced 500 MB of spill traffic), while
// preventing the K=8-style 184-VGPR balloon. No atomics: u64 packed per-thread
// histogram (6-bit fields, max 16/field), wave shuffle-reduce, per-wave LDS
// slots, per-block plain global store.
// ---------------------------------------------------------------------------
__global__ __launch_bounds__(THREADS, 4) void hist_kernel(const float* __restrict__ x,
                                                          const float* __restrict__ protos,
                                                          unsigned int* __restrict__ partial) {
    const int b    = blockIdx.y;
    const int tid  = threadIdx.x;
    const int lane = tid & 63;
    const int wave = tid >> 6;

    float p0[NP], p1[NP];
#pragma unroll
    for (int p = 0; p < NP; ++p) {
        p0[p] = protos[p * 2 + 0];
        p1[p] = protos[p * 2 + 1];
    }

    const float4* x0 = (const float4*)(x + (size_t)b * 2 * DHW);
    const float4* x1 = (const float4*)(x + (size_t)b * 2 * DHW + DHW);
    const int i0 = blockIdx.x * THREADS + tid;

    // issue all loads first -> max memory-level parallelism
    float4 a[K_ITERS], c[K_ITERS];
#pragma unroll
    for (int k = 0; k < K_ITERS; ++k) {
        a[k] = x0[i0 + k * STRIDE4];
        c[k] = x1[i0 + k * STRIDE4];
    }

    unsigned long long packed = 0ull;   // 10 x 6-bit counters
#pragma unroll
    for (int k = 0; k < K_ITERS; ++k) {
        float xa[4] = {a[k].x, a[k].y, a[k].z, a[k].w};
        float xc[4] = {c[k].x, c[k].y, c[k].z, c[k].w};
#pragma unroll
        for (int j = 0; j < 4; ++j) {
            float best = xa[j] * p0[0] + xc[j] * p1[0];
            int   bi   = 0;
#pragma unroll
            for (int p = 1; p < NP; ++p) {
                float sim = xa[j] * p0[p] + xc[j] * p1[p];
                if (sim > best) { best = sim; bi = p; }   // strict > == np.argmax first-max
            }
            packed += 1ull << (6 * bi);
        }
    }

    // wave-level reduction of each 6-bit field, then per-wave LDS slot
    __shared__ unsigned int smem[THREADS / 64][NP];
#pragma unroll
    for (int p = 0; p < NP; ++p) {
        unsigned int cc = (unsigned int)((packed >> (6 * p)) & 63ull);
#pragma unroll
        for (int off = 32; off > 0; off >>= 1)
            cc += __shfl_xor(cc, off, 64);
        if (lane == 0) smem[wave][p] = cc;
    }
    __syncthreads();

    if (tid < NP) {
        unsigned int t = smem[0][tid] + smem[1][tid] + smem[2][tid] + smem[3][tid];
        partial[((size_t)b * BLOCKS_X + blockIdx.x) * NP + tid] = t;   // plain store
    }
}

// ---------------------------------------------------------------------------
// Kernel 2: sum partials -> counts; pool = counts @ protos; contrastive loss.
// ---------------------------------------------------------------------------
__global__ void finalize_kernel(const unsigned int* __restrict__ partial,
                                const float* __restrict__ protos,
                                const float* __restrict__ queue0,
                                const float* __restrict__ queue1,
                                float* __restrict__ out) {
    __shared__ float scount[NB][NP];
    __shared__ float ploss[NB];
    const int t = threadIdx.x;

    if (t < NB * NP) {
        const int b = t / NP, p = t % NP;
        unsigned int s = 0;
#pragma unroll 8
        for (int j = 0; j < BLOCKS_X; ++j)
            s += partial[((size_t)b * BLOCKS_X + j) * NP + p];
        scount[b][p] = (float)s;
    }
    __syncthreads();

    if (t < NB) {
        float pool0 = 0.f, pool1 = 0.f;
#pragma unroll
        for (int p = 0; p < NP; ++p) {
            pool0 += scount[t][p] * protos[p * 2 + 0];
            pool1 += scount[t][p] * protos[p * 2 + 1];
        }
        float n = fmaxf(sqrtf(pool0 * pool0 + pool1 * pool1), 1e-12f);
        float pn0 = pool0 / n, pn1 = pool1 / n;

        float ln[NQ];
        float maxlog = -INFINITY;
#pragma unroll
        for (int q = 0; q < NQ; ++q) {
            float f0 = queue0[q * 2], f1 = queue0[q * 2 + 1];
            float nn = fmaxf(sqrtf(f0 * f0 + f1 * f1), 1e-12f);
            float l  = (pn0 * f0 + pn1 * f1) / nn * TEMP_INV;
            ln[q] = l;
            maxlog = fmaxf(maxlog, l);
        }
        float lneg = 0.f;
#pragma unroll
        for (int q = 0; q < NQ; ++q) lneg += expf(ln[q] - maxlog);

        float lsum = 0.f;
#pragma unroll
        for (int q = 0; q < NQ; ++q) {
            float f0 = queue1[q * 2], f1 = queue1[q * 2 + 1];
            float nn = fmaxf(sqrtf(f0 * f0 + f1 * f1), 1e-12f);
            float lp = (pn0 * f0 + pn1 * f1) / nn * TEMP_INV - maxlog;
            float v  = fmaxf(lneg + expf(lp), 1e-4f);
            lsum += -(lp - logf(v));
        }
        ploss[t] = lsum / (float)NQ;
    }
    __syncthreads();
    if (t == 0) {
        float s = 0.f;
#pragma unroll
        for (int i = 0; i < NB; ++i) s += ploss[i];
        out[0] = s / (float)NB;
    }
}

extern "C" void kernel_launch(void* const* d_in, const int* in_sizes, int n_in,
                              void* d_out, int out_size, void* d_ws, size_t ws_size,
                              hipStream_t stream) {
    const float* x      = (const float*)d_in[0];
    // d_in[1] = label — cancels out of the loss exactly; never read.
    const float* protos = (const float*)d_in[2];
    const float* q0     = (const float*)d_in[3];
    const float* q1     = (const float*)d_in[4];
    float* out          = (float*)d_out;

    unsigned int* partial = (unsigned int*)d_ws;   // [8*256][10] u32 = 80 KB
    // No memset needed: every block unconditionally writes its partial row.

    dim3 grid(BLOCKS_X, NB);
    hist_kernel<<<grid, THREADS, 0, stream>>>(x, protos, partial);
    finalize_kernel<<<1, 128, 0, stream>>>(partial, protos, q0, q1, out);
}

// Round 5
// 127.201 us; speedup vs baseline: 2.0161x; 1.4155x over previous
//
#include <hip/hip_runtime.h>
#include <math.h>

#define NP 10          // num prototypes
#define NQ 10          // queue length
#define NB 8           // batch
#define TEMP_INV (1.0f/0.07f)
#define DHW (64*128*128)       // 1,048,576 voxels per sample
#define BLOCKS_X 256           // blocks per sample -> 2048 blocks total (8/CU)
#define THREADS 256
#define K_ITERS 4              // float4-pairs per thread: 256*256*4*4 == DHW
#define STRIDE4 (BLOCKS_X*THREADS)   // 65536 float4s

// ---------------------------------------------------------------------------
// Kernel 1: per-voxel argmax over 10 prototypes -> per-block partial histogram.
// Register-pressure control is STRUCTURAL, not via launch bounds:
//   - NO __launch_bounds__ min-waves arg (R3/R4 proved any cap -> scratch
//     spill: 500 MB / 166 MB of HBM spill traffic).
//   - '#pragma unroll 1' on the k-loop with loads inside the iteration:
//     loop-carried state is just `packed` + pointers (~50 VGPR natural),
//     so the allocator picks high occupancy on its own and latency is
//     hidden by TLP (8 waves/SIMD) instead of hoisted-load ILP.
// No atomics: u64 packed per-thread histogram (6-bit fields, max 16/field),
// wave shuffle-reduce, per-wave LDS slots, per-block plain global store.
// ---------------------------------------------------------------------------
__global__ void hist_kernel(const float* __restrict__ x,
                            const float* __restrict__ protos,
                            unsigned int* __restrict__ partial) {
    const int b    = blockIdx.y;
    const int tid  = threadIdx.x;
    const int lane = tid & 63;
    const int wave = tid >> 6;

    float p0[NP], p1[NP];
#pragma unroll
    for (int p = 0; p < NP; ++p) {
        p0[p] = protos[p * 2 + 0];
        p1[p] = protos[p * 2 + 1];
    }

    const float4* x0 = (const float4*)(x + (size_t)b * 2 * DHW);
    const float4* x1 = (const float4*)(x + (size_t)b * 2 * DHW + DHW);
    const int i0 = blockIdx.x * THREADS + tid;

    unsigned long long packed = 0ull;   // 10 x 6-bit counters

#pragma unroll 1
    for (int k = 0; k < K_ITERS; ++k) {
        float4 a = x0[i0 + k * STRIDE4];   // both loads issued back-to-back,
        float4 c = x1[i0 + k * STRIDE4];   // then one vmcnt wait before compute
        float xa[4] = {a.x, a.y, a.z, a.w};
        float xc[4] = {c.x, c.y, c.z, c.w};
#pragma unroll
        for (int j = 0; j < 4; ++j) {
            float best = xa[j] * p0[0] + xc[j] * p1[0];
            int   bi   = 0;
#pragma unroll
            for (int p = 1; p < NP; ++p) {
                float sim = xa[j] * p0[p] + xc[j] * p1[p];
                if (sim > best) { best = sim; bi = p; }   // strict > == np.argmax first-max
            }
            packed += 1ull << (6 * bi);
        }
    }

    // wave-level reduction of each 6-bit field, then per-wave LDS slot
    __shared__ unsigned int smem[THREADS / 64][NP];
#pragma unroll
    for (int p = 0; p < NP; ++p) {
        unsigned int cc = (unsigned int)((packed >> (6 * p)) & 63ull);
#pragma unroll
        for (int off = 32; off > 0; off >>= 1)
            cc += __shfl_xor(cc, off, 64);
        if (lane == 0) smem[wave][p] = cc;
    }
    __syncthreads();

    if (tid < NP) {
        unsigned int t = smem[0][tid] + smem[1][tid] + smem[2][tid] + smem[3][tid];
        partial[((size_t)b * BLOCKS_X + blockIdx.x) * NP + tid] = t;   // plain store
    }
}

// ---------------------------------------------------------------------------
// Kernel 2: sum partials -> counts; pool = counts @ protos; contrastive loss.
// ---------------------------------------------------------------------------
__global__ void finalize_kernel(const unsigned int* __restrict__ partial,
                                const float* __restrict__ protos,
                                const float* __restrict__ queue0,
                                const float* __restrict__ queue1,
                                float* __restrict__ out) {
    __shared__ float scount[NB][NP];
    __shared__ float ploss[NB];
    const int t = threadIdx.x;

    if (t < NB * NP) {
        const int b = t / NP, p = t % NP;
        unsigned int s = 0;
#pragma unroll 8
        for (int j = 0; j < BLOCKS_X; ++j)
            s += partial[((size_t)b * BLOCKS_X + j) * NP + p];
        scount[b][p] = (float)s;
    }
    __syncthreads();

    if (t < NB) {
        float pool0 = 0.f, pool1 = 0.f;
#pragma unroll
        for (int p = 0; p < NP; ++p) {
            pool0 += scount[t][p] * protos[p * 2 + 0];
            pool1 += scount[t][p] * protos[p * 2 + 1];
        }
        float n = fmaxf(sqrtf(pool0 * pool0 + pool1 * pool1), 1e-12f);
        float pn0 = pool0 / n, pn1 = pool1 / n;

        float ln[NQ];
        float maxlog = -INFINITY;
#pragma unroll
        for (int q = 0; q < NQ; ++q) {
            float f0 = queue0[q * 2], f1 = queue0[q * 2 + 1];
            float nn = fmaxf(sqrtf(f0 * f0 + f1 * f1), 1e-12f);
            float l  = (pn0 * f0 + pn1 * f1) / nn * TEMP_INV;
            ln[q] = l;
            maxlog = fmaxf(maxlog, l);
        }
        float lneg = 0.f;
#pragma unroll
        for (int q = 0; q < NQ; ++q) lneg += expf(ln[q] - maxlog);

        float lsum = 0.f;
#pragma unroll
        for (int q = 0; q < NQ; ++q) {
            float f0 = queue1[q * 2], f1 = queue1[q * 2 + 1];
            float nn = fmaxf(sqrtf(f0 * f0 + f1 * f1), 1e-12f);
            float lp = (pn0 * f0 + pn1 * f1) / nn * TEMP_INV - maxlog;
            float v  = fmaxf(lneg + expf(lp), 1e-4f);
            lsum += -(lp - logf(v));
        }
        ploss[t] = lsum / (float)NQ;
    }
    __syncthreads();
    if (t == 0) {
        float s = 0.f;
#pragma unroll
        for (int i = 0; i < NB; ++i) s += ploss[i];
        out[0] = s / (float)NB;
    }
}

extern "C" void kernel_launch(void* const* d_in, const int* in_sizes, int n_in,
                              void* d_out, int out_size, void* d_ws, size_t ws_size,
                              hipStream_t stream) {
    const float* x      = (const float*)d_in[0];
    // d_in[1] = label — cancels out of the loss exactly; never read.
    const float* protos = (const float*)d_in[2];
    const float* q0     = (const float*)d_in[3];
    const float* q1     = (const float*)d_in[4];
    float* out          = (float*)d_out;

    unsigned int* partial = (unsigned int*)d_ws;   // [8*256][10] u32 = 80 KB
    // No memset needed: every block unconditionally writes its partial row.

    dim3 grid(BLOCKS_X, NB);
    hist_kernel<<<grid, THREADS, 0, stream>>>(x, protos, partial);
    finalize_kernel<<<1, 128, 0, stream>>>(partial, protos, q0, q1, out);
}

// Round 6
// 124.576 us; speedup vs baseline: 2.0586x; 1.0211x over previous
//
#include <hip/hip_runtime.h>
#include <math.h>

#define NP 10          // num prototypes
#define NQ 10          // queue length
#define NB 8           // batch
#define TEMP_INV (1.0f/0.07f)
#define DHW (64*128*128)       // 1,048,576 voxels per sample
#define BLOCKS_X 256           // blocks per sample -> 2048 blocks total (8/CU)
#define THREADS 256
#define K_ITERS 4              // float4-pairs per thread: 256*256*4*4 == DHW
#define STRIDE4 (BLOCKS_X*THREADS)   // 65536 float4s

// ---------------------------------------------------------------------------
// Kernel 1: per-voxel argmax over 10 prototypes -> per-block partial histogram.
// Register-pressure control is STRUCTURAL, not via launch bounds:
//   - NO __launch_bounds__ min-waves arg (R3/R4: any cap -> scratch spill,
//     500 MB / 166 MB of HBM spill traffic).
//   - '#pragma unroll 2' on the k-loop: 4 float4 loads in flight (~60 VGPR
//     natural -> >=6 waves/SIMD from the allocator's own choice). R5's
//     unroll-1 had only 2 loads in flight -> latency-bound (~90 cyc compute
//     vs 350-900 cyc latency per round-trip).
// No atomics: u64 packed per-thread histogram (6-bit fields, max 16/field),
// wave shuffle-reduce, per-wave LDS slots, per-block plain global store.
// ---------------------------------------------------------------------------
__global__ void hist_kernel(const float* __restrict__ x,
                            const float* __restrict__ protos,
                            unsigned int* __restrict__ partial) {
    const int b    = blockIdx.y;
    const int tid  = threadIdx.x;
    const int lane = tid & 63;
    const int wave = tid >> 6;

    float p0[NP], p1[NP];
#pragma unroll
    for (int p = 0; p < NP; ++p) {
        p0[p] = protos[p * 2 + 0];
        p1[p] = protos[p * 2 + 1];
    }

    const float4* x0 = (const float4*)(x + (size_t)b * 2 * DHW);
    const float4* x1 = (const float4*)(x + (size_t)b * 2 * DHW + DHW);
    const int i0 = blockIdx.x * THREADS + tid;

    unsigned long long packed = 0ull;   // 10 x 6-bit counters

#pragma unroll 2
    for (int k = 0; k < K_ITERS; ++k) {
        float4 a = x0[i0 + k * STRIDE4];
        float4 c = x1[i0 + k * STRIDE4];
        float xa[4] = {a.x, a.y, a.z, a.w};
        float xc[4] = {c.x, c.y, c.z, c.w};
#pragma unroll
        for (int j = 0; j < 4; ++j) {
            float best = xa[j] * p0[0] + xc[j] * p1[0];
            int   bi   = 0;
#pragma unroll
            for (int p = 1; p < NP; ++p) {
                float sim = xa[j] * p0[p] + xc[j] * p1[p];
                if (sim > best) { best = sim; bi = p; }   // strict > == np.argmax first-max
            }
            packed += 1ull << (6 * bi);
        }
    }

    // wave-level reduction of each 6-bit field, then per-wave LDS slot
    __shared__ unsigned int smem[THREADS / 64][NP];
#pragma unroll
    for (int p = 0; p < NP; ++p) {
        unsigned int cc = (unsigned int)((packed >> (6 * p)) & 63ull);
#pragma unroll
        for (int off = 32; off > 0; off >>= 1)
            cc += __shfl_xor(cc, off, 64);
        if (lane == 0) smem[wave][p] = cc;
    }
    __syncthreads();

    if (tid < NP) {
        unsigned int t = smem[0][tid] + smem[1][tid] + smem[2][tid] + smem[3][tid];
        partial[((size_t)b * BLOCKS_X + blockIdx.x) * NP + tid] = t;   // plain store
    }
}

// ---------------------------------------------------------------------------
// Kernel 2: sum partials -> counts; pool = counts @ protos; contrastive loss.
// Parallel partial-sum: 8 threads per (b,p) pair (640 threads), 32 loads each
// with unroll-8 MLP, LDS tree to combine. R5's 80-thread serial version was
// ~5 us of pure load latency.
// ---------------------------------------------------------------------------
#define THREADS_F 640

__global__ void finalize_kernel(const unsigned int* __restrict__ partial,
                                const float* __restrict__ protos,
                                const float* __restrict__ queue0,
                                const float* __restrict__ queue1,
                                float* __restrict__ out) {
    __shared__ unsigned int psum[NB * NP][8];
    __shared__ float scount[NB][NP];
    __shared__ float ploss[NB];
    const int t = threadIdx.x;

    {
        const int g = t >> 3;        // 0..79 -> (b,p)
        const int s = t & 7;
        const int b = g / NP, p = g % NP;
        unsigned int acc = 0;
#pragma unroll 8
        for (int j = s; j < BLOCKS_X; j += 8)
            acc += partial[((size_t)b * BLOCKS_X + j) * NP + p];
        psum[g][s] = acc;
    }
    __syncthreads();

    if (t < NB * NP) {
        unsigned int s = 0;
#pragma unroll
        for (int k = 0; k < 8; ++k) s += psum[t][k];
        scount[t / NP][t % NP] = (float)s;
    }
    __syncthreads();

    if (t < NB) {
        float pool0 = 0.f, pool1 = 0.f;
#pragma unroll
        for (int p = 0; p < NP; ++p) {
            pool0 += scount[t][p] * protos[p * 2 + 0];
            pool1 += scount[t][p] * protos[p * 2 + 1];
        }
        float n = fmaxf(sqrtf(pool0 * pool0 + pool1 * pool1), 1e-12f);
        float pn0 = pool0 / n, pn1 = pool1 / n;

        float ln[NQ];
        float maxlog = -INFINITY;
#pragma unroll
        for (int q = 0; q < NQ; ++q) {
            float f0 = queue0[q * 2], f1 = queue0[q * 2 + 1];
            float nn = fmaxf(sqrtf(f0 * f0 + f1 * f1), 1e-12f);
            float l  = (pn0 * f0 + pn1 * f1) / nn * TEMP_INV;
            ln[q] = l;
            maxlog = fmaxf(maxlog, l);
        }
        float lneg = 0.f;
#pragma unroll
        for (int q = 0; q < NQ; ++q) lneg += expf(ln[q] - maxlog);

        float lsum = 0.f;
#pragma unroll
        for (int q = 0; q < NQ; ++q) {
            float f0 = queue1[q * 2], f1 = queue1[q * 2 + 1];
            float nn = fmaxf(sqrtf(f0 * f0 + f1 * f1), 1e-12f);
            float lp = (pn0 * f0 + pn1 * f1) / nn * TEMP_INV - maxlog;
            float v  = fmaxf(lneg + expf(lp), 1e-4f);
            lsum += -(lp - logf(v));
        }
        ploss[t] = lsum / (float)NQ;
    }
    __syncthreads();
    if (t == 0) {
        float s = 0.f;
#pragma unroll
        for (int i = 0; i < NB; ++i) s += ploss[i];
        out[0] = s / (float)NB;
    }
}

extern "C" void kernel_launch(void* const* d_in, const int* in_sizes, int n_in,
                              void* d_out, int out_size, void* d_ws, size_t ws_size,
                              hipStream_t stream) {
    const float* x      = (const float*)d_in[0];
    // d_in[1] = label — cancels out of the loss exactly; never read.
    const float* protos = (const float*)d_in[2];
    const float* q0     = (const float*)d_in[3];
    const float* q1     = (const float*)d_in[4];
    float* out          = (float*)d_out;

    unsigned int* partial = (unsigned int*)d_ws;   // [8*256][10] u32 = 80 KB
    // No memset needed: every block unconditionally writes its partial row.

    dim3 grid(BLOCKS_X, NB);
    hist_kernel<<<grid, THREADS, 0, stream>>>(x, protos, partial);
    finalize_kernel<<<1, THREADS_F, 0, stream>>>(partial, protos, q0, q1, out);
}

// Round 7
// 124.422 us; speedup vs baseline: 2.0611x; 1.0012x over previous
//
#include <hip/hip_runtime.h>
#include <math.h>

#define NP 10          // num prototypes
#define NQ 10          // queue length
#define NB 8           // batch
#define TEMP_INV (1.0f/0.07f)
#define DHW (64*128*128)       // 1,048,576 voxels per sample
#define BLOCKS_X 512           // blocks per sample -> 4096 blocks total (16/CU)
#define THREADS 256
#define STRIDE4 (BLOCKS_X*THREADS)   // 131072 float4s; 2 k-iters cover DHW/4

// ---------------------------------------------------------------------------
// Kernel 1: per-voxel argmax over 10 prototypes -> per-block partial histogram.
// Register-pressure control is STRUCTURAL (no __launch_bounds__ cap — R3/R4
// proved any cap -> scratch spill, 500/166 MB of HBM spill traffic):
//   - K=2 fully unrolled: all 4 float4 loads issued back-to-back (one vmcnt
//     wait, max MLP) while total live state stays ~64-72 VGPR -> allocator
//     keeps near-full occupancy on its own. 4096 blocks = 16/CU for TLP.
// No atomics: u64 packed per-thread histogram (6-bit fields, max 8/field),
// wave shuffle-reduce, per-wave LDS slots, per-block plain global store.
// ---------------------------------------------------------------------------
__global__ void hist_kernel(const float* __restrict__ x,
                            const float* __restrict__ protos,
                            unsigned int* __restrict__ partial) {
    const int b    = blockIdx.y;
    const int tid  = threadIdx.x;
    const int lane = tid & 63;
    const int wave = tid >> 6;

    float p0[NP], p1[NP];
#pragma unroll
    for (int p = 0; p < NP; ++p) {
        p0[p] = protos[p * 2 + 0];
        p1[p] = protos[p * 2 + 1];
    }

    const float4* x0 = (const float4*)(x + (size_t)b * 2 * DHW);
    const float4* x1 = (const float4*)(x + (size_t)b * 2 * DHW + DHW);
    const int i0 = blockIdx.x * THREADS + tid;

    // all four loads in flight before any compute
    float4 a0 = x0[i0];
    float4 a1 = x0[i0 + STRIDE4];
    float4 c0 = x1[i0];
    float4 c1 = x1[i0 + STRIDE4];

    unsigned long long packed = 0ull;   // 10 x 6-bit counters (max 8/field)

    float xa[8] = {a0.x, a0.y, a0.z, a0.w, a1.x, a1.y, a1.z, a1.w};
    float xc[8] = {c0.x, c0.y, c0.z, c0.w, c1.x, c1.y, c1.z, c1.w};
#pragma unroll
    for (int j = 0; j < 8; ++j) {
        float best = xa[j] * p0[0] + xc[j] * p1[0];
        int   bi   = 0;
#pragma unroll
        for (int p = 1; p < NP; ++p) {
            float sim = xa[j] * p0[p] + xc[j] * p1[p];
            if (sim > best) { best = sim; bi = p; }   // strict > == np.argmax first-max
        }
        packed += 1ull << (6 * bi);
    }

    // wave-level reduction of each 6-bit field, then per-wave LDS slot
    __shared__ unsigned int smem[THREADS / 64][NP];
#pragma unroll
    for (int p = 0; p < NP; ++p) {
        unsigned int cc = (unsigned int)((packed >> (6 * p)) & 63ull);
#pragma unroll
        for (int off = 32; off > 0; off >>= 1)
            cc += __shfl_xor(cc, off, 64);
        if (lane == 0) smem[wave][p] = cc;
    }
    __syncthreads();

    if (tid < NP) {
        unsigned int t = smem[0][tid] + smem[1][tid] + smem[2][tid] + smem[3][tid];
        partial[((size_t)b * BLOCKS_X + blockIdx.x) * NP + tid] = t;   // plain store
    }
}

// ---------------------------------------------------------------------------
// Kernel 2: sum partials -> counts; pool = counts @ protos; contrastive loss.
// 8 threads per (b,p) pair (640 threads), 64 loads each with unroll-8 MLP,
// LDS tree to combine.
// ---------------------------------------------------------------------------
#define THREADS_F 640

__global__ void finalize_kernel(const unsigned int* __restrict__ partial,
                                const float* __restrict__ protos,
                                const float* __restrict__ queue0,
                                const float* __restrict__ queue1,
                                float* __restrict__ out) {
    __shared__ unsigned int psum[NB * NP][8];
    __shared__ float scount[NB][NP];
    __shared__ float ploss[NB];
    const int t = threadIdx.x;

    {
        const int g = t >> 3;        // 0..79 -> (b,p)
        const int s = t & 7;
        const int b = g / NP, p = g % NP;
        unsigned int acc = 0;
#pragma unroll 8
        for (int j = s; j < BLOCKS_X; j += 8)
            acc += partial[((size_t)b * BLOCKS_X + j) * NP + p];
        psum[g][s] = acc;
    }
    __syncthreads();

    if (t < NB * NP) {
        unsigned int s = 0;
#pragma unroll
        for (int k = 0; k < 8; ++k) s += psum[t][k];
        scount[t / NP][t % NP] = (float)s;
    }
    __syncthreads();

    if (t < NB) {
        float pool0 = 0.f, pool1 = 0.f;
#pragma unroll
        for (int p = 0; p < NP; ++p) {
            pool0 += scount[t][p] * protos[p * 2 + 0];
            pool1 += scount[t][p] * protos[p * 2 + 1];
        }
        float n = fmaxf(sqrtf(pool0 * pool0 + pool1 * pool1), 1e-12f);
        float pn0 = pool0 / n, pn1 = pool1 / n;

        float ln[NQ];
        float maxlog = -INFINITY;
#pragma unroll
        for (int q = 0; q < NQ; ++q) {
            float f0 = queue0[q * 2], f1 = queue0[q * 2 + 1];
            float nn = fmaxf(sqrtf(f0 * f0 + f1 * f1), 1e-12f);
            float l  = (pn0 * f0 + pn1 * f1) / nn * TEMP_INV;
            ln[q] = l;
            maxlog = fmaxf(maxlog, l);
        }
        float lneg = 0.f;
#pragma unroll
        for (int q = 0; q < NQ; ++q) lneg += expf(ln[q] - maxlog);

        float lsum = 0.f;
#pragma unroll
        for (int q = 0; q < NQ; ++q) {
            float f0 = queue1[q * 2], f1 = queue1[q * 2 + 1];
            float nn = fmaxf(sqrtf(f0 * f0 + f1 * f1), 1e-12f);
            float lp = (pn0 * f0 + pn1 * f1) / nn * TEMP_INV - maxlog;
            float v  = fmaxf(lneg + expf(lp), 1e-4f);
            lsum += -(lp - logf(v));
        }
        ploss[t] = lsum / (float)NQ;
    }
    __syncthreads();
    if (t == 0) {
        float s = 0.f;
#pragma unroll
        for (int i = 0; i < NB; ++i) s += ploss[i];
        out[0] = s / (float)NB;
    }
}

extern "C" void kernel_launch(void* const* d_in, const int* in_sizes, int n_in,
                              void* d_out, int out_size, void* d_ws, size_t ws_size,
                              hipStream_t stream) {
    const float* x      = (const float*)d_in[0];
    // d_in[1] = label — cancels out of the loss exactly; never read.
    const float* protos = (const float*)d_in[2];
    const float* q0     = (const float*)d_in[3];
    const float* q1     = (const float*)d_in[4];
    float* out          = (float*)d_out;

    unsigned int* partial = (unsigned int*)d_ws;   // [8*512][10] u32 = 160 KB
    // No memset needed: every block unconditionally writes its partial row.

    dim3 grid(BLOCKS_X, NB);
    hist_kernel<<<grid, THREADS, 0, stream>>>(x, protos, partial);
    finalize_kernel<<<1, THREADS_F, 0, stream>>>(partial, protos, q0, q1, out);
}